// Round 2
// baseline (1944.693 us; speedup 1.0000x reference)
//
#include <hip/hip_runtime.h>

#define EPS 1e-16f

// ws layout: [0, nc*64)  = per-column feature sums (float)
//            [nc*64, nc*65) = per-column counts (float)

__global__ void zero_ws_kernel(float* __restrict__ ws, const int* __restrict__ num_cols_p) {
    const int nc = *num_cols_p;
    const long total = (long)nc * 65;
    for (long idx = blockIdx.x * (long)blockDim.x + threadIdx.x; idx < total;
         idx += (long)gridDim.x * blockDim.x) {
        ws[idx] = 0.0f;
    }
}

// One thread per (nnz, float4-chunk): 16 threads cover one row of 64 features.
__global__ void scatter_kernel(const float4* __restrict__ vals4,
                               const int* __restrict__ cols,
                               float* __restrict__ ws,
                               const int* __restrict__ num_cols_p,
                               int nnz) {
    const long t = blockIdx.x * (long)blockDim.x + threadIdx.x;
    const long total = (long)nnz * 16;
    if (t >= total) return;
    const int i  = (int)(t >> 4);
    const int jv = (int)(t & 15);
    const int c  = cols[i];
    const float4 v = vals4[t];
    float* dst = ws + (long)c * 64 + jv * 4;
    atomicAdd(dst + 0, v.x);
    atomicAdd(dst + 1, v.y);
    atomicAdd(dst + 2, v.z);
    atomicAdd(dst + 3, v.w);
    if (jv == 0) {
        const int nc = *num_cols_p;
        atomicAdd(ws + (long)nc * 64 + c, 1.0f);
    }
}

// In-place: sums -> means
__global__ void finalize_kernel(float* __restrict__ ws, const int* __restrict__ num_cols_p) {
    const int nc = *num_cols_p;
    const float* cnt = ws + (long)nc * 64;
    const long total = (long)nc * 64;
    for (long idx = blockIdx.x * (long)blockDim.x + threadIdx.x; idx < total;
         idx += (long)gridDim.x * blockDim.x) {
        const int c = (int)(idx >> 6);
        ws[idx] = ws[idx] / (cnt[c] + EPS);
    }
}

// One thread per (nnz, float4-chunk): out[i] = mean[col[i]]
__global__ void gather_kernel(const float* __restrict__ ws,
                              const int* __restrict__ cols,
                              float4* __restrict__ out4,
                              int nnz) {
    const long t = blockIdx.x * (long)blockDim.x + threadIdx.x;
    const long total = (long)nnz * 16;
    if (t >= total) return;
    const int i  = (int)(t >> 4);
    const int jv = (int)(t & 15);
    const int c  = cols[i];
    const float4* mean4 = (const float4*)(ws) + (long)c * 16;
    out4[t] = mean4[jv];
}

extern "C" void kernel_launch(void* const* d_in, const int* in_sizes, int n_in,
                              void* d_out, int out_size, void* d_ws, size_t ws_size,
                              hipStream_t stream) {
    const float* values     = (const float*)d_in[0];
    const int*   indices    = (const int*)d_in[1];
    const int*   num_cols_p = (const int*)d_in[2];

    const int nnz = in_sizes[0] / 64;           // values is [nnz, 64]
    const int* cols = indices + nnz;            // indices[1] (seg = column index)

    float* ws = (float*)d_ws;

    const int blk = 256;

    // 1. zero sums + counts (grid-stride; size read on-device)
    zero_ws_kernel<<<4096, blk, 0, stream>>>(ws, num_cols_p);

    // 2. scatter atomic accumulate
    {
        const long total = (long)nnz * 16;
        const int grid = (int)((total + blk - 1) / blk);
        scatter_kernel<<<grid, blk, 0, stream>>>((const float4*)values, cols, ws,
                                                 num_cols_p, nnz);
    }

    // 3. sums -> means
    finalize_kernel<<<4096, blk, 0, stream>>>(ws, num_cols_p);

    // 4. gather means to output
    {
        const long total = (long)nnz * 16;
        const int grid = (int)((total + blk - 1) / blk);
        gather_kernel<<<grid, blk, 0, stream>>>(ws, cols, (float4*)d_out, nnz);
    }
}

// Round 3
// 517.261 us; speedup vs baseline: 3.7596x; 3.7596x over previous
//
#include <hip/hip_runtime.h>

#define EPS 1e-16f

// d_ws layout (int units):
//   [0, nnz)        perm   : nnz row-indices grouped by column
//   [nnz, ...)      rest   : hist[nc] | start[nc+1] | cursor[nc]   (nc read on device)
// total: (nnz + 3*nc + 1) * 4 bytes  (~8.6 MB here, well under prior 13 MB use)

__global__ void init_kernel(int* __restrict__ rest, const int* __restrict__ nc_p) {
    const int nc = *nc_p;
    int* hist   = rest;
    int* cursor = rest + 2 * nc + 1;
    for (int i = blockIdx.x * blockDim.x + threadIdx.x; i < nc;
         i += gridDim.x * blockDim.x) {
        hist[i] = 0;
        cursor[i] = 0;
    }
}

__global__ void hist_kernel(const int* __restrict__ cols, int* __restrict__ rest, int nnz) {
    int* hist = rest;
    for (int i = blockIdx.x * blockDim.x + threadIdx.x; i < nnz;
         i += gridDim.x * blockDim.x) {
        atomicAdd(&hist[cols[i]], 1);
    }
}

// Single-block exclusive scan: 1024 threads x 64 serial elements = 65536/chunk.
__global__ void scan_kernel(int* __restrict__ rest, const int* __restrict__ nc_p) {
    const int nc = *nc_p;
    int* hist  = rest;
    int* start = rest + nc;
    __shared__ int wave_tot[16];
    __shared__ int s_carry;
    if (threadIdx.x == 0) s_carry = 0;
    __syncthreads();
    const int tid  = threadIdx.x;
    const int lane = tid & 63;
    const int wid  = tid >> 6;
    const int PER  = 64;
    for (int base = 0; base < nc; base += 1024 * PER) {
        const int lo = base + tid * PER;
        int s = 0;
        for (int j = 0; j < PER; ++j) {
            int idx = lo + j;
            if (idx < nc) s += hist[idx];
        }
        // wave-inclusive scan of per-thread sums (no barriers needed)
        int inc = s;
        for (int off = 1; off < 64; off <<= 1) {
            int t = __shfl_up(inc, off);
            if (lane >= off) inc += t;
        }
        if (lane == 63) wave_tot[wid] = inc;
        __syncthreads();
        int woff = 0;
        for (int w = 0; w < wid; ++w) woff += wave_tot[w];
        int running = s_carry + woff + inc - s;  // exclusive prefix of this run
        for (int j = 0; j < PER; ++j) {
            int idx = lo + j;
            if (idx < nc) { start[idx] = running; running += hist[idx]; }
        }
        __syncthreads();
        if (tid == 1023) s_carry += woff + inc;  // grand total of this chunk
        __syncthreads();
    }
    if (threadIdx.x == 0) start[nc] = s_carry;   // == nnz
}

__global__ void permute_kernel(const int* __restrict__ cols, int* __restrict__ perm,
                               int* __restrict__ rest, const int* __restrict__ nc_p,
                               int nnz) {
    const int nc = *nc_p;
    const int* start = rest + nc;
    int* cursor = rest + 2 * nc + 1;
    for (int i = blockIdx.x * blockDim.x + threadIdx.x; i < nnz;
         i += gridDim.x * blockDim.x) {
        const int c = cols[i];
        const int pos = start[c] + atomicAdd(&cursor[c], 1);
        perm[pos] = i;
    }
}

// One wave per column (grid-stride). Lane = (row-group g=lane>>4, float4 slot jv=lane&15).
// Each wave-load pulls 4 rows x 256B = 1KB. Reduce groups via shfl_xor, write mean
// directly to every owning output row (no mean table, no separate gather).
__global__ void pool_kernel(const float4* __restrict__ vals4,
                            const int* __restrict__ perm,
                            const int* __restrict__ rest,
                            const int* __restrict__ nc_p,
                            float4* __restrict__ out4) {
    const int nc = *nc_p;
    const int* start = rest + nc;
    const int lane = threadIdx.x & 63;
    const int g  = lane >> 4;
    const int jv = lane & 15;
    const int wavesPerBlock = blockDim.x >> 6;
    const int wave = blockIdx.x * wavesPerBlock + (threadIdx.x >> 6);
    const int totalWaves = gridDim.x * wavesPerBlock;
    for (int c = wave; c < nc; c += totalWaves) {
        const int s = start[c];
        const int e = start[c + 1];
        const int n = e - s;
        if (n == 0) continue;
        float4 acc = make_float4(0.f, 0.f, 0.f, 0.f);
        for (int k = s + g; k < e; k += 4) {
            const int i = perm[k];
            const float4 v = vals4[(long)i * 16 + jv];
            acc.x += v.x; acc.y += v.y; acc.z += v.z; acc.w += v.w;
        }
        for (int off = 16; off < 64; off <<= 1) {
            acc.x += __shfl_xor(acc.x, off);
            acc.y += __shfl_xor(acc.y, off);
            acc.z += __shfl_xor(acc.z, off);
            acc.w += __shfl_xor(acc.w, off);
        }
        const float inv = 1.0f / ((float)n + EPS);
        const float4 mean = make_float4(acc.x * inv, acc.y * inv, acc.z * inv, acc.w * inv);
        for (int k = s + g; k < e; k += 4) {
            const int i = perm[k];
            out4[(long)i * 16 + jv] = mean;
        }
    }
}

extern "C" void kernel_launch(void* const* d_in, const int* in_sizes, int n_in,
                              void* d_out, int out_size, void* d_ws, size_t ws_size,
                              hipStream_t stream) {
    const float* values = (const float*)d_in[0];
    const int*   indices = (const int*)d_in[1];
    const int*   nc_p    = (const int*)d_in[2];

    const int nnz = in_sizes[0] / 64;      // values is [nnz, 64]
    const int* cols = indices + nnz;       // indices[1] = column index per nnz

    int* perm = (int*)d_ws;
    int* rest = perm + nnz;

    const int blk = 256;
    const int grid_nnz = (nnz + blk - 1) / blk;

    init_kernel<<<256, blk, 0, stream>>>(rest, nc_p);
    hist_kernel<<<grid_nnz, blk, 0, stream>>>(cols, rest, nnz);
    scan_kernel<<<1, 1024, 0, stream>>>(rest, nc_p);
    permute_kernel<<<grid_nnz, blk, 0, stream>>>(cols, perm, rest, nc_p, nnz);
    pool_kernel<<<4096, blk, 0, stream>>>((const float4*)values, perm, rest, nc_p,
                                          (float4*)d_out);
}